// Round 10
// baseline (172.934 us; speedup 1.0000x reference)
//
#include <hip/hip_runtime.h>
#include <hip/hip_bf16.h>
#include <math.h>

// Problem constants (BN, N, FIN, FO, H) from the reference
#define BN_   4
#define NN_   2048
#define FIN_  128
#define FO_   64
#define H_    4
#define D_    256   // FO*H

typedef __attribute__((ext_vector_type(8))) short bf16x8;   // 8 bf16 = 4 VGPRs
typedef __attribute__((ext_vector_type(4))) float floatx4;  // MFMA C/D frag

#define LOG2E 1.4426950408889634f
#define C2F   (0.2f * 1.4426950408889634f)   // 0.2 * log2(e)

#if __has_builtin(__builtin_amdgcn_exp2f)
#define EXP2(x) __builtin_amdgcn_exp2f(x)
#else
#define EXP2(x) exp2f(x)
#endif

__device__ __forceinline__ float bf2f(short u) {
    union { unsigned int i; float f; } v;
    v.i = ((unsigned int)(unsigned short)u) << 16;
    return v.f;
}
__device__ __forceinline__ short f2bf(float f) {
    union { float f; unsigned int u; } v; v.f = f;
    unsigned int r = v.u + 0x7fffu + ((v.u >> 16) & 1u);  // RNE
    return (short)(unsigned short)(r >> 16);
}

// pack two floats to two bf16 (RNE) in one dword; elem0 in low 16 bits
#if defined(__BF16_MANT_DIG__)
typedef __bf16 bfr2 __attribute__((ext_vector_type(2)));
__device__ __forceinline__ unsigned int pack_bf16(float a, float b) {
    union { bfr2 h; unsigned int u; } v;
    v.h = (bfr2){(__bf16)a, (__bf16)b};
    return v.u;
}
#else
__device__ __forceinline__ unsigned int pack_bf16(float a, float b) {
    return ((unsigned int)(unsigned short)f2bf(a)) |
           (((unsigned int)(unsigned short)f2bf(b)) << 16);
}
#endif

// load 8 consecutive fp32 and round to a bf16x8 MFMA fragment
__device__ __forceinline__ bf16x8 load8f(const float* __restrict__ p) {
    floatx4 a = *(const floatx4*)p;
    floatx4 b = *(const floatx4*)(p + 4);
    union { bf16x8 v; unsigned int u[4]; } r;
    r.u[0] = pack_bf16(a[0], a[1]);
    r.u[1] = pack_bf16(a[2], a[3]);
    r.u[2] = pack_bf16(b[0], b[1]);
    r.u[3] = pack_bf16(b[2], b[3]);
    return r.v;
}

// ---------------------------------------------------------------------------
// Kernel 1: projection -> PT2 (fragment-tiled bf16) + sS (raw s_src) +
// eT/eT2 (exp2(s_tgt*log2e), exp2(0.2*s_tgt*log2e)) per (h, j).
// Round-10: eT/eT2 feed the attn kernel's factorized softmax weights
// (exp-monotonicity: exp(leaky(p)) = max(exp(p), exp(0.2p)), and
// exp(a+b+c) = exp(a)exp(b)exp(c)) -- removes the per-element exp2 from
// attn's inner loop entirely. Body otherwise = round-8's verified kernel.
// PT2 layout (IDENTICAL to rounds 6-9):
//   elem(h, f, j) -> (h*64 + (j>>5))*2048 + (f>>4)*512 + ((j>>3)&3)*128
//                    + (f&15)*8 + (j&7)        [per-batch slab]
// ---------------------------------------------------------------------------
__global__ __launch_bounds__(256) void proj_kernel(
    const float* __restrict__ x,      // (BN, NN, FIN) fp32
    const float* __restrict__ wproj,  // (D, FIN) fp32
    const float* __restrict__ ssrc,   // (H, FO) fp32
    const float* __restrict__ stgt,   // (H, FO) fp32
    short* __restrict__ pt,           // (nb) PT2 slabs, 1 MiB each
    float* __restrict__ sS,           // (nb*H, NN) fp32  raw s_src
    float* __restrict__ eT,           // (nb*H, NN) fp32  exp2(s_tgt*log2e)
    float* __restrict__ eT2,          // (nb*H, NN) fp32  exp2(.2*s_tgt*log2e)
    int b0)
{
    __shared__ short ptl[64][264];    // [f][j_local], +8 pad (33792 B)

    const int tid  = threadIdx.x;
    const int wave = tid >> 6;
    const int lane = tid & 63;
    const int l16  = lane & 15;
    const int quad = lane >> 4;

    const int b_rel = blockIdx.z;
    const int b  = b0 + b_rel;
    const int h  = blockIdx.y;            // head
    const int j0 = blockIdx.x * 256 + wave * 64;

    floatx4 acc[4][4];
#pragma unroll
    for (int mi = 0; mi < 4; ++mi)
#pragma unroll
        for (int nj = 0; nj < 4; ++nj)
            acc[mi][nj] = (floatx4){0.f, 0.f, 0.f, 0.f};

#pragma unroll
    for (int kc = 0; kc < 4; ++kc) {
        const int c = kc * 32 + quad * 8;
        bf16x8 afr[4], bfr[4];
#pragma unroll
        for (int mi = 0; mi < 4; ++mi) {
            int f = mi * 16 + l16;                // f within head
            int srow = f * H_ + h;                // W_proj row (flat d = f*H+h)
            afr[mi] = load8f(wproj + srow * FIN_ + c);
        }
#pragma unroll
        for (int nj = 0; nj < 4; ++nj) {
            int j = j0 + nj * 16 + l16;
            bfr[nj] = load8f(x + ((size_t)b * NN_ + j) * FIN_ + c);
        }
#pragma unroll
        for (int mi = 0; mi < 4; ++mi)
#pragma unroll
            for (int nj = 0; nj < 4; ++nj)
                acc[mi][nj] = __builtin_amdgcn_mfma_f32_16x16x32_bf16(
                    afr[mi], bfr[nj], acc[mi][nj], 0, 0, 0);
    }

    // ---- stage C-fragments into the [f][j_local] LDS tile ----
    // lane holds (f = mi*16 + quad*4 + r, j_local = wave*64 + nj*16 + l16)
#pragma unroll
    for (int mi = 0; mi < 4; ++mi)
#pragma unroll
        for (int r = 0; r < 4; ++r)
#pragma unroll
            for (int nj = 0; nj < 4; ++nj)
                ptl[mi * 16 + quad * 4 + r][wave * 64 + nj * 16 + l16] =
                    f2bf(acc[mi][nj][r]);

    // ---- score dot-products from fp32 accumulators (register-local) ----
    float wsv[4][4], wtv[4][4];
#pragma unroll
    for (int mi = 0; mi < 4; ++mi)
#pragma unroll
        for (int r = 0; r < 4; ++r) {
            int f = mi * 16 + quad * 4 + r;
            wsv[mi][r] = ssrc[h * FO_ + f];
            wtv[mi][r] = stgt[h * FO_ + f];
        }
    const size_t sbase = ((size_t)b_rel * H_ + h) * NN_;
#pragma unroll
    for (int nj = 0; nj < 4; ++nj) {
        float ps = 0.f, pg = 0.f;
#pragma unroll
        for (int mi = 0; mi < 4; ++mi)
#pragma unroll
            for (int r = 0; r < 4; ++r) {
                ps = fmaf(wsv[mi][r], acc[mi][nj][r], ps);
                pg = fmaf(wtv[mi][r], acc[mi][nj][r], pg);
            }
        ps += __shfl_xor(ps, 16, 64); ps += __shfl_xor(ps, 32, 64);
        pg += __shfl_xor(pg, 16, 64); pg += __shfl_xor(pg, 32, 64);
        if (quad == 0) {
            int j = j0 + nj * 16 + l16;
            sS[sbase + j]  = ps;
            eT[sbase + j]  = EXP2(pg * LOG2E);
            eT2[sbase + j] = EXP2(pg * C2F);
        }
    }

    __syncthreads();

    // ---- dense PT2 store: block's 32 KB range is CONTIGUOUS in PT2 ----
    const size_t base = ((size_t)b_rel * H_ + h) * (size_t)(64 * 2048)
                      + (size_t)(blockIdx.x * 8) * 2048;
#pragma unroll
    for (int p = 0; p < 8; ++p) {
        const int uid  = p * 256 + tid;           // 0..2047
        const int mi   = (uid >> 6) & 3;          // == wave
        const int l    = uid & 63;                // == lane
        const int tile = uid >> 8;                // wave-uniform
        const int f    = mi * 16 + (l & 15);
        const int js   = tile * 32 + (l >> 4) * 8;
        bf16x8 v = *(const bf16x8*)&ptl[f][js];   // 16B-aligned (264|8, js|8)
        *(bf16x8*)&pt[base + (size_t)uid * 8] = v;  // dense: lane*16B
    }
}

// ---------------------------------------------------------------------------
// Kernel 2: fused attention, 4 heads per block, i-tile = 16.
// Round-10 change (structure otherwise = round-8's verified 53.5 us):
// factorized softmax weight -- the per-element exp2 is replaced by
//   wv = max(es[u]*et[j], es2[u]*et2[j]) * ea[i,j]
// where ea = exp2(adj*log2e) is computed ONCE per jt (shared by 4 heads;
// exp2 count 67M -> ~17M), and et/et2 come from proj via L2-hot dense
// broadcast loads. st LDS array deleted (LDS 51.2 -> 33.8 KB).
// max() == the leaky_relu piecewise select because exp is monotonic.
// ---------------------------------------------------------------------------
#define RSTRIDE 65   // LDS row stride (pad +1 col to break bank alignment)
#define WSLOT   (RSTRIDE * 16 + 16)   // 1056 floats per wave slot

__global__ __launch_bounds__(512, 2) void attn_kernel(
    const float* __restrict__ adj,    // (BN, NN, NN) fp32
    const short* __restrict__ pt,     // PT2 slabs (see proj_kernel)
    const float* __restrict__ sS,     // (nb*H, NN) fp32
    const float* __restrict__ eT,     // (nb*H, NN) fp32
    const float* __restrict__ eT2,    // (nb*H, NN) fp32
    const float* __restrict__ bias,   // (D,) fp32
    float* __restrict__ out,          // (BN, NN, D) fp32
    int b0)
{
    __shared__ union {
        float adjs[8][16][36];        // per-wave adj tile (18432 B)
        float red[8][WSLOT];          // cross-wave reduction (33792 B)
    } sm;

    const int tid  = threadIdx.x;
    const int w    = tid >> 6;        // wave = 256-wide j-slice
    const int lane = tid & 63;
    const int l16  = lane & 15;
    const int quad = lane >> 4;
    const int r8   = lane >> 3;       // 0..7  (adj stage row-in-group)
    const int c4   = (lane & 7) * 4;  // 0,4..28 (adj stage col, floats)

    const int b_rel = blockIdx.z;
    const int b  = b0 + b_rel;
    const int i0 = blockIdx.x * 16;

    const short* pt2_b = pt + (size_t)b_rel * H_ * (size_t)(64 * 2048);
    const size_t sb = (size_t)b_rel * H_ * NN_;

    // per-lane s_src exp factors for my i-row (row = l16), all heads
    float es[4], es2[4];
#pragma unroll
    for (int h = 0; h < 4; ++h) {
        float sv = sS[sb + (size_t)h * NN_ + i0 + l16];
        es[h]  = EXP2(sv * LOG2E);
        es2[h] = EXP2(sv * C2F);
    }

    // et/et2 bases for this wave's j-slice (+ quad offset folded in)
    const int qo = quad * 8;
    const float* etp[4];
    const float* et2p[4];
#pragma unroll
    for (int h = 0; h < 4; ++h) {
        etp[h]  = eT  + sb + (size_t)h * NN_ + w * 256 + qo;
        et2p[h] = eT2 + sb + (size_t)h * NN_ + w * 256 + qo;
    }

    // adj stage base: rows i0.., cols w*256..
    const float* adj_base = adj + ((size_t)b * NN_ + i0) * NN_ + w * 256;

    floatx4 acc[4][4];                // [head][f-block], 64 regs
#pragma unroll
    for (int h = 0; h < 4; ++h)
#pragma unroll
        for (int K = 0; K < 4; ++K)
            acc[h][K] = (floatx4){0.f, 0.f, 0.f, 0.f};
    float ls[4] = {0.f, 0.f, 0.f, 0.f};

    // prologue: dense-load + stage adj tile jt=0
    floatx4 areg0 = *(const floatx4*)(adj_base + (size_t)r8 * NN_ + c4);
    floatx4 areg1 = *(const floatx4*)(adj_base + (size_t)(8 + r8) * NN_ + c4);
    *(floatx4*)&sm.adjs[w][r8][c4]     = areg0;
    *(floatx4*)&sm.adjs[w][8 + r8][c4] = areg1;

    const int lo8 = lane * 8;         // PT2 per-lane element offset

#pragma unroll
    for (int jt = 0; jt < 8; ++jt) {              // 8 iters x 32 j per wave
        const int o = jt * 32;                    // static element offset

        // T14 issue-early: dense global loads for the NEXT adj tile
        if (jt < 7) {
            areg0 = *(const floatx4*)(adj_base + (size_t)r8 * NN_ + o + 32 + c4);
            areg1 = *(const floatx4*)(adj_base + (size_t)(8 + r8) * NN_ + o + 32 + c4);
        }

        // A-values for this tile from LDS (wave-private, already staged)
        floatx4 ajA = *(const floatx4*)&sm.adjs[w][l16][qo];
        floatx4 ajB = *(const floatx4*)&sm.adjs[w][l16][qo + 4];

        // ea = exp2(adj*log2e), ONCE per jt, shared by all 4 heads
        floatx4 eaA, eaB;
#pragma unroll
        for (int k = 0; k < 4; ++k) {
            eaA[k] = EXP2(ajA[k] * LOG2E);
            eaB[k] = EXP2(ajB[k] * LOG2E);
        }

#pragma unroll
        for (int u = 0; u < 4; ++u) {
            // dense 1 KB fragment loads from PT2 (uniform base + lane*16B)
            const short* fb = pt2_b + ((size_t)u * 64 + (w * 8 + jt)) * 2048 + lo8;
            bf16x8 bfr[4];
#pragma unroll
            for (int K = 0; K < 4; ++K)
                bfr[K] = *(const bf16x8*)(fb + K * 512);

            // et/et2: L2-hot quad-broadcast dense loads
            floatx4 etA  = *(const floatx4*)(etp[u] + o);
            floatx4 etB  = *(const floatx4*)(etp[u] + o + 4);
            floatx4 et2A = *(const floatx4*)(et2p[u] + o);
            floatx4 et2B = *(const floatx4*)(et2p[u] + o + 4);

            const float eu = es[u], eu2 = es2[u];
            float w0 = fmaxf(eu * etA[0], eu2 * et2A[0]) * eaA[0];
            float w1 = fmaxf(eu * etA[1], eu2 * et2A[1]) * eaA[1];
            float w2 = fmaxf(eu * etA[2], eu2 * et2A[2]) * eaA[2];
            float w3 = fmaxf(eu * etA[3], eu2 * et2A[3]) * eaA[3];
            float w4 = fmaxf(eu * etB[0], eu2 * et2B[0]) * eaB[0];
            float w5 = fmaxf(eu * etB[1], eu2 * et2B[1]) * eaB[1];
            float w6 = fmaxf(eu * etB[2], eu2 * et2B[2]) * eaB[2];
            float w7 = fmaxf(eu * etB[3], eu2 * et2B[3]) * eaB[3];
            ls[u] += ((w0 + w1) + (w2 + w3)) + ((w4 + w5) + (w6 + w7));
            union { bf16x8 v; unsigned int u4[4]; } a0;
            a0.u4[0] = pack_bf16(w0, w1);
            a0.u4[1] = pack_bf16(w2, w3);
            a0.u4[2] = pack_bf16(w4, w5);
            a0.u4[3] = pack_bf16(w6, w7);
#pragma unroll
            for (int K = 0; K < 4; ++K)
                acc[u][K] = __builtin_amdgcn_mfma_f32_16x16x32_bf16(
                    a0.v, bfr[K], acc[u][K], 0, 0, 0);
        }

        // T14 write-late: stage next tile after this tile's LDS reads
        if (jt < 7) {
            *(floatx4*)&sm.adjs[w][r8][c4]     = areg0;
            *(floatx4*)&sm.adjs[w][8 + r8][c4] = areg1;
        }
    }

    // wave-local row-sums over quads (row = l16 in A-layout)
#pragma unroll
    for (int h = 0; h < 4; ++h) {
        ls[h] += __shfl_xor(ls[h], 16, 64);
        ls[h] += __shfl_xor(ls[h], 32, 64);
    }

    // epilogue: 4 head-chunks of 16 rows; 8-wave LDS reduction per chunk
#pragma unroll
    for (int h = 0; h < 4; ++h) {
        __syncthreads();   // h=0: all main-loop LDS reads done; h>0: prev chunk
#pragma unroll
        for (int K = 0; K < 4; ++K)
#pragma unroll
            for (int r = 0; r < 4; ++r)
                sm.red[w][(quad * 4 + r) * RSTRIDE + K * 16 + l16] = acc[h][K][r];
        if (quad == 0)
            sm.red[w][16 * RSTRIDE + l16] = ls[h];
        __syncthreads();
#pragma unroll
        for (int p = 0; p < 2; ++p) {
            int e   = tid + p * 512;
            int row = e >> 6;
            int col = e & 63;
            float s = 0.f, l = 0.f;
#pragma unroll
            for (int ww = 0; ww < 8; ++ww) {
                s += sm.red[ww][row * RSTRIDE + col];
                l += sm.red[ww][16 * RSTRIDE + row];
            }
            float v = s / l + bias[h * FO_ + col];
            v = (v > 0.f) ? v : expm1f(v);        // elu (fp32 out)
            out[((size_t)b * NN_ + i0 + row) * D_ + h * FO_ + col] = v;
        }
    }
}

// ---------------------------------------------------------------------------
// Launch: ws is 256 MiB (round-9 fill discovery) -> nb = 4 always: ONE proj
// + ONE attn dispatch. The round-9 staging/copy chain is reverted (it split
// attn sublinearly and added dispatches).
// ---------------------------------------------------------------------------
extern "C" void kernel_launch(void* const* d_in, const int* in_sizes, int n_in,
                              void* d_out, int out_size, void* d_ws, size_t ws_size,
                              hipStream_t stream) {
    const float* x     = (const float*)d_in[0];   // (4,2048,128) fp32
    const float* adj   = (const float*)d_in[1];   // (4,2048,2048) fp32
    const float* wproj = (const float*)d_in[2];   // (256,128) fp32
    const float* ssrc  = (const float*)d_in[3];   // (4,64) fp32
    const float* stgt  = (const float*)d_in[4];   // (4,64) fp32
    const float* bias  = (const float*)d_in[5];   // (256,) fp32
    float* out = (float*)d_out;                   // (4,2048,256) fp32

    // ws layout per batch: PT2 slab (1 MiB) + sS/eT/eT2 (96 KiB)
    const size_t SLAB  = (size_t)D_ * NN_ * 2;          // bf16 PT2
    const size_t SSLAB = (size_t)3 * H_ * NN_ * 4;      // fp32 sS+eT+eT2
    int nb = (int)(ws_size / (SLAB + SSLAB));
    if (nb < 1) nb = 1;
    if (nb > 4) nb = 4;

    short* pt = (short*)d_ws;
    float* sv  = (float*)((char*)d_ws + (size_t)nb * SLAB);
    float* sS  = sv;
    float* eT  = sv + (size_t)nb * H_ * NN_;
    float* eT2 = sv + (size_t)2 * nb * H_ * NN_;

    for (int bb0 = 0; bb0 < BN_; bb0 += nb) {
        int cnt = (BN_ - bb0 < nb) ? (BN_ - bb0) : nb;
        proj_kernel<<<dim3(NN_ / 256, H_, cnt), 256, 0, stream>>>(
            x, wproj, ssrc, stgt, pt, sS, eT, eT2, bb0);
        attn_kernel<<<dim3(NN_ / 16, 1, cnt), 512, 0, stream>>>(
            adj, pt, sS, eT, eT2, bias, out, bb0);
    }
}

// Round 11
// 163.132 us; speedup vs baseline: 1.0601x; 1.0601x over previous
//
#include <hip/hip_runtime.h>
#include <hip/hip_bf16.h>
#include <math.h>

// Problem constants (BN, N, FIN, FO, H) from the reference
#define BN_   4
#define NN_   2048
#define FIN_  128
#define FO_   64
#define H_    4
#define D_    256   // FO*H

typedef __attribute__((ext_vector_type(8))) short bf16x8;   // 8 bf16 = 4 VGPRs
typedef __attribute__((ext_vector_type(4))) float floatx4;  // MFMA C/D frag

#define LOG2E 1.4426950408889634f

#if __has_builtin(__builtin_amdgcn_exp2f)
#define EXP2(x) __builtin_amdgcn_exp2f(x)
#else
#define EXP2(x) exp2f(x)
#endif

__device__ __forceinline__ float bf2f(short u) {
    union { unsigned int i; float f; } v;
    v.i = ((unsigned int)(unsigned short)u) << 16;
    return v.f;
}
__device__ __forceinline__ short f2bf(float f) {
    union { float f; unsigned int u; } v; v.f = f;
    unsigned int r = v.u + 0x7fffu + ((v.u >> 16) & 1u);  // RNE
    return (short)(unsigned short)(r >> 16);
}

// pack two floats to two bf16 (RNE) in one dword; elem0 in low 16 bits
#if defined(__BF16_MANT_DIG__)
typedef __bf16 bfr2 __attribute__((ext_vector_type(2)));
__device__ __forceinline__ unsigned int pack_bf16(float a, float b) {
    union { bfr2 h; unsigned int u; } v;
    v.h = (bfr2){(__bf16)a, (__bf16)b};
    return v.u;
}
#else
__device__ __forceinline__ unsigned int pack_bf16(float a, float b) {
    return ((unsigned int)(unsigned short)f2bf(a)) |
           (((unsigned int)(unsigned short)f2bf(b)) << 16);
}
#endif

// load 8 consecutive fp32 and round to a bf16x8 MFMA fragment
__device__ __forceinline__ bf16x8 load8f(const float* __restrict__ p) {
    floatx4 a = *(const floatx4*)p;
    floatx4 b = *(const floatx4*)(p + 4);
    union { bf16x8 v; unsigned int u[4]; } r;
    r.u[0] = pack_bf16(a[0], a[1]);
    r.u[1] = pack_bf16(a[2], a[3]);
    r.u[2] = pack_bf16(b[0], b[1]);
    r.u[3] = pack_bf16(b[2], b[3]);
    return r.v;
}

// attention score -> exp weight (bit-identical across rounds)
__device__ __forceinline__ float score_exp(float ssv, float stv, float av) {
    float s = ssv + stv;
    s = fmaxf(s, 0.2f * s);            // leaky_relu(0.2)
    return EXP2((s + av) * LOG2E);
}

// ---------------------------------------------------------------------------
// Kernel 1: projection -> PT2 (fragment-tiled bf16) + s_src/s_tgt.
// EXACT round-8 kernel (verified in the 161.0 us best round).
// PT2 layout:
//   elem(h, f, j) -> (h*64 + (j>>5))*2048 + (f>>4)*512 + ((j>>3)&3)*128
//                    + (f&15)*8 + (j&7)        [per-batch slab]
// ---------------------------------------------------------------------------
__global__ __launch_bounds__(256) void proj_kernel(
    const float* __restrict__ x,      // (BN, NN, FIN) fp32
    const float* __restrict__ wproj,  // (D, FIN) fp32
    const float* __restrict__ ssrc,   // (H, FO) fp32
    const float* __restrict__ stgt,   // (H, FO) fp32
    short* __restrict__ pt,           // (nb) PT2 slabs, 1 MiB each
    float* __restrict__ sS,           // (nb*H, NN) fp32
    float* __restrict__ sT,           // (nb*H, NN) fp32
    int b0)
{
    __shared__ short ptl[64][264];    // [f][j_local], +8 pad (33792 B)

    const int tid  = threadIdx.x;
    const int wave = tid >> 6;
    const int lane = tid & 63;
    const int l16  = lane & 15;
    const int quad = lane >> 4;

    const int b_rel = blockIdx.z;
    const int b  = b0 + b_rel;
    const int h  = blockIdx.y;            // head
    const int j0 = blockIdx.x * 256 + wave * 64;

    floatx4 acc[4][4];
#pragma unroll
    for (int mi = 0; mi < 4; ++mi)
#pragma unroll
        for (int nj = 0; nj < 4; ++nj)
            acc[mi][nj] = (floatx4){0.f, 0.f, 0.f, 0.f};

#pragma unroll
    for (int kc = 0; kc < 4; ++kc) {
        const int c = kc * 32 + quad * 8;
        bf16x8 afr[4], bfr[4];
#pragma unroll
        for (int mi = 0; mi < 4; ++mi) {
            int f = mi * 16 + l16;                // f within head
            int srow = f * H_ + h;                // W_proj row (flat d = f*H+h)
            afr[mi] = load8f(wproj + srow * FIN_ + c);
        }
#pragma unroll
        for (int nj = 0; nj < 4; ++nj) {
            int j = j0 + nj * 16 + l16;
            bfr[nj] = load8f(x + ((size_t)b * NN_ + j) * FIN_ + c);
        }
#pragma unroll
        for (int mi = 0; mi < 4; ++mi)
#pragma unroll
            for (int nj = 0; nj < 4; ++nj)
                acc[mi][nj] = __builtin_amdgcn_mfma_f32_16x16x32_bf16(
                    afr[mi], bfr[nj], acc[mi][nj], 0, 0, 0);
    }

    // ---- stage C-fragments into the [f][j_local] LDS tile ----
    // lane holds (f = mi*16 + quad*4 + r, j_local = wave*64 + nj*16 + l16)
#pragma unroll
    for (int mi = 0; mi < 4; ++mi)
#pragma unroll
        for (int r = 0; r < 4; ++r)
#pragma unroll
            for (int nj = 0; nj < 4; ++nj)
                ptl[mi * 16 + quad * 4 + r][wave * 64 + nj * 16 + l16] =
                    f2bf(acc[mi][nj][r]);

    // ---- score dot-products from fp32 accumulators (register-local) ----
    float wsv[4][4], wtv[4][4];
#pragma unroll
    for (int mi = 0; mi < 4; ++mi)
#pragma unroll
        for (int r = 0; r < 4; ++r) {
            int f = mi * 16 + quad * 4 + r;
            wsv[mi][r] = ssrc[h * FO_ + f];
            wtv[mi][r] = stgt[h * FO_ + f];
        }
    const size_t sbase = ((size_t)b_rel * H_ + h) * NN_;
#pragma unroll
    for (int nj = 0; nj < 4; ++nj) {
        float ps = 0.f, pg = 0.f;
#pragma unroll
        for (int mi = 0; mi < 4; ++mi)
#pragma unroll
            for (int r = 0; r < 4; ++r) {
                ps = fmaf(wsv[mi][r], acc[mi][nj][r], ps);
                pg = fmaf(wtv[mi][r], acc[mi][nj][r], pg);
            }
        ps += __shfl_xor(ps, 16, 64); ps += __shfl_xor(ps, 32, 64);
        pg += __shfl_xor(pg, 16, 64); pg += __shfl_xor(pg, 32, 64);
        if (quad == 0) {
            int j = j0 + nj * 16 + l16;
            sS[sbase + j] = ps;
            sT[sbase + j] = pg;
        }
    }

    __syncthreads();

    // ---- dense PT2 store: block's 32 KB range is CONTIGUOUS in PT2 ----
    const size_t base = ((size_t)b_rel * H_ + h) * (size_t)(64 * 2048)
                      + (size_t)(blockIdx.x * 8) * 2048;
#pragma unroll
    for (int p = 0; p < 8; ++p) {
        const int uid  = p * 256 + tid;           // 0..2047
        const int mi   = (uid >> 6) & 3;          // == wave
        const int l    = uid & 63;                // == lane
        const int tile = uid >> 8;                // wave-uniform
        const int f    = mi * 16 + (l & 15);
        const int js   = tile * 32 + (l >> 4) * 8;
        bf16x8 v = *(const bf16x8*)&ptl[f][js];   // 16B-aligned (264|8, js|8)
        *(bf16x8*)&pt[base + (size_t)uid * 8] = v;  // dense: lane*16B
    }
}

// ---------------------------------------------------------------------------
// Kernel 2: fused attention, 4 heads per block, i-tile = 16.
// Body = EXACT round-8 kernel (53.5 us verified). Round-11 adds ONE change:
// XCD-aware block remap (T1). Evidence: attn time ~ 55-60 cyc per 1 KB
// dense wave-load (r2/r5/r6/r10 four-point fit); FETCH_SIZE ~= adj only, so
// the 512 MB of PT2 re-reads (128 i-blocks x 1 MiB slab per batch) are
// served by L3/far-L2 at ~10 TB/s -> ~51 us ~= the whole attn time.
// Remap: flat = x + 128*z; XCD = flat&7 (round-robin model, m09/T1).
// Assign batch = xcd>>1, i_blk = (xcd&1)*64 + (flat>>3) -> all blocks of
// batch z run on XCDs {2z, 2z+1}, whose 4 MiB L2 then keeps the batch's
// 1 MiB PT2 slab resident (reuse interval ~0.4 us; streaming adj evicts
// only ~100 KB between re-touches). Bijective; bit-identical output.
// ---------------------------------------------------------------------------
#define RSTRIDE 65   // LDS row stride (pad +1 col to break bank alignment)
#define WSLOT   (RSTRIDE * 16 + 16)   // 1056 floats per wave slot

__global__ __launch_bounds__(512, 2) void attn_kernel(
    const float* __restrict__ adj,    // (BN, NN, NN) fp32
    const short* __restrict__ pt,     // PT2 slabs (see proj_kernel)
    const float* __restrict__ sS,     // (nb*H, NN) fp32
    const float* __restrict__ sT,     // (nb*H, NN) fp32
    const float* __restrict__ bias,   // (D,) fp32
    float* __restrict__ out,          // (BN, NN, D) fp32
    int b0)
{
    __shared__ union {
        struct {
            float adjs[8][16][36];    // per-wave adj tile (18432 B)
            float st[8][4][256];      // per-wave s_tgt slices (32768 B)
        } m;
        float red[8][WSLOT];          // cross-wave reduction (33792 B)
    } sm;

    const int tid  = threadIdx.x;
    const int w    = tid >> 6;        // wave = 256-wide j-slice
    const int lane = tid & 63;
    const int l16  = lane & 15;
    const int quad = lane >> 4;
    const int r8   = lane >> 3;       // 0..7  (adj stage row-in-group)
    const int c4   = (lane & 7) * 4;  // 0,4..28 (adj stage col, floats)

    // ---- T1 XCD-aware remap (identity unless full 4-batch grid) ----
    int bx = blockIdx.x, bz = blockIdx.z;
    if (gridDim.z == 4 && gridDim.x == 128) {
        const int flat = bx + 128 * bz;       // HW flat workgroup id
        const int xcd  = flat & 7;            // round-robin XCD model
        bz = xcd >> 1;                        // batch: 2 XCDs per batch
        bx = (xcd & 1) * 64 + (flat >> 3);    // i-block within batch
    }
    const int b_rel = bz;
    const int b  = b0 + b_rel;
    const int i0 = bx * 16;

    const short* pt2_b = pt + (size_t)b_rel * H_ * (size_t)(64 * 2048);
    const size_t sb = (size_t)b_rel * H_ * NN_;

    // stage s_tgt slices for all 4 heads (wave-private; no barrier needed)
    {
        const int t = lane * 4;
#pragma unroll
        for (int h = 0; h < 4; ++h)
            *(floatx4*)&sm.m.st[w][h][t] =
                *(const floatx4*)&sT[sb + (size_t)h * NN_ + w * 256 + t];
    }

    // per-lane s_src for my i-row (row = l16), all heads
    float ssv[4];
#pragma unroll
    for (int h = 0; h < 4; ++h)
        ssv[h] = sS[sb + (size_t)h * NN_ + i0 + l16];

    // adj stage base: rows i0.., cols w*256..
    const float* adj_base = adj + ((size_t)b * NN_ + i0) * NN_ + w * 256;

    floatx4 acc[4][4];                // [head][f-block], 64 regs
#pragma unroll
    for (int h = 0; h < 4; ++h)
#pragma unroll
        for (int K = 0; K < 4; ++K)
            acc[h][K] = (floatx4){0.f, 0.f, 0.f, 0.f};
    float ls[4] = {0.f, 0.f, 0.f, 0.f};

    // prologue: dense-load + stage adj tile jt=0
    floatx4 areg0 = *(const floatx4*)(adj_base + (size_t)r8 * NN_ + c4);
    floatx4 areg1 = *(const floatx4*)(adj_base + (size_t)(8 + r8) * NN_ + c4);
    *(floatx4*)&sm.m.adjs[w][r8][c4]     = areg0;
    *(floatx4*)&sm.m.adjs[w][8 + r8][c4] = areg1;

    const int lo8 = lane * 8;         // PT2 per-lane element offset

#pragma unroll
    for (int jt = 0; jt < 8; ++jt) {              // 8 iters x 32 j per wave
        const int o  = jt * 32;                   // static element offset
        const int qo = quad * 8;

        // T14 issue-early: dense global loads for the NEXT adj tile
        if (jt < 7) {
            areg0 = *(const floatx4*)(adj_base + (size_t)r8 * NN_ + o + 32 + c4);
            areg1 = *(const floatx4*)(adj_base + (size_t)(8 + r8) * NN_ + o + 32 + c4);
        }

        // A-values for this tile from LDS (wave-private, already staged)
        floatx4 ajA = *(const floatx4*)&sm.m.adjs[w][l16][qo];
        floatx4 ajB = *(const floatx4*)&sm.m.adjs[w][l16][qo + 4];

#pragma unroll
        for (int u = 0; u < 4; ++u) {
            // dense 1 KB fragment loads from PT2 (uniform base + lane*16B)
            const short* fb = pt2_b + ((size_t)u * 64 + (w * 8 + jt)) * 2048 + lo8;
            bf16x8 bfr[4];
#pragma unroll
            for (int K = 0; K < 4; ++K)
                bfr[K] = *(const bf16x8*)(fb + K * 512);

            const float* stp = &sm.m.st[w][u][qo];
            floatx4 stA = *(const floatx4*)(stp + o);
            floatx4 stB = *(const floatx4*)(stp + o + 4);

            float w0 = score_exp(ssv[u], stA[0], ajA[0]);
            float w1 = score_exp(ssv[u], stA[1], ajA[1]);
            float w2 = score_exp(ssv[u], stA[2], ajA[2]);
            float w3 = score_exp(ssv[u], stA[3], ajA[3]);
            float w4 = score_exp(ssv[u], stB[0], ajB[0]);
            float w5 = score_exp(ssv[u], stB[1], ajB[1]);
            float w6 = score_exp(ssv[u], stB[2], ajB[2]);
            float w7 = score_exp(ssv[u], stB[3], ajB[3]);
            ls[u] += ((w0 + w1) + (w2 + w3)) + ((w4 + w5) + (w6 + w7));
            union { bf16x8 v; unsigned int u4[4]; } a0;
            a0.u4[0] = pack_bf16(w0, w1);
            a0.u4[1] = pack_bf16(w2, w3);
            a0.u4[2] = pack_bf16(w4, w5);
            a0.u4[3] = pack_bf16(w6, w7);
#pragma unroll
            for (int K = 0; K < 4; ++K)
                acc[u][K] = __builtin_amdgcn_mfma_f32_16x16x32_bf16(
                    a0.v, bfr[K], acc[u][K], 0, 0, 0);
        }

        // T14 write-late: stage next tile after this tile's LDS reads
        if (jt < 7) {
            *(floatx4*)&sm.m.adjs[w][r8][c4]     = areg0;
            *(floatx4*)&sm.m.adjs[w][8 + r8][c4] = areg1;
        }
    }

    // wave-local row-sums over quads (row = l16 in A-layout)
#pragma unroll
    for (int h = 0; h < 4; ++h) {
        ls[h] += __shfl_xor(ls[h], 16, 64);
        ls[h] += __shfl_xor(ls[h], 32, 64);
    }

    // epilogue: 4 head-chunks of 16 rows; 8-wave LDS reduction per chunk
#pragma unroll
    for (int h = 0; h < 4; ++h) {
        __syncthreads();   // h=0: all main-loop LDS reads done; h>0: prev chunk
#pragma unroll
        for (int K = 0; K < 4; ++K)
#pragma unroll
            for (int r = 0; r < 4; ++r)
                sm.red[w][(quad * 4 + r) * RSTRIDE + K * 16 + l16] = acc[h][K][r];
        if (quad == 0)
            sm.red[w][16 * RSTRIDE + l16] = ls[h];
        __syncthreads();
#pragma unroll
        for (int p = 0; p < 2; ++p) {
            int e   = tid + p * 512;
            int row = e >> 6;
            int col = e & 63;
            float s = 0.f, l = 0.f;
#pragma unroll
            for (int ww = 0; ww < 8; ++ww) {
                s += sm.red[ww][row * RSTRIDE + col];
                l += sm.red[ww][16 * RSTRIDE + row];
            }
            float v = s / l + bias[h * FO_ + col];
            v = (v > 0.f) ? v : expm1f(v);        // elu (fp32 out)
            out[((size_t)b * NN_ + i0 + row) * D_ + h * FO_ + col] = v;
        }
    }
}

// ---------------------------------------------------------------------------
extern "C" void kernel_launch(void* const* d_in, const int* in_sizes, int n_in,
                              void* d_out, int out_size, void* d_ws, size_t ws_size,
                              hipStream_t stream) {
    const float* x     = (const float*)d_in[0];   // (4,2048,128) fp32
    const float* adj   = (const float*)d_in[1];   // (4,2048,2048) fp32
    const float* wproj = (const float*)d_in[2];   // (256,128) fp32
    const float* ssrc  = (const float*)d_in[3];   // (4,64) fp32
    const float* stgt  = (const float*)d_in[4];   // (4,64) fp32
    const float* bias  = (const float*)d_in[5];   // (256,) fp32
    float* out = (float*)d_out;                   // (4,2048,256) fp32

    // ws layout per batch: PT2 slab (1 MiB) + s_src/s_tgt (64 KiB)
    const size_t SLAB  = (size_t)D_ * NN_ * 2;          // bf16 PT2
    const size_t SSLAB = (size_t)2 * H_ * NN_ * 4;      // fp32 sS+sT
    int nb = (int)(ws_size / (SLAB + SSLAB));
    if (nb < 1) nb = 1;
    if (nb > 4) nb = 4;

    short* pt = (short*)d_ws;
    float* sv = (float*)((char*)d_ws + (size_t)nb * SLAB);
    float* sS = sv;
    float* sT = sv + (size_t)nb * H_ * NN_;

    for (int bb0 = 0; bb0 < BN_; bb0 += nb) {
        int cnt = (BN_ - bb0 < nb) ? (BN_ - bb0) : nb;
        proj_kernel<<<dim3(NN_ / 256, H_, cnt), 256, 0, stream>>>(
            x, wproj, ssrc, stgt, pt, sS, sT, bb0);
        attn_kernel<<<dim3(NN_ / 16, 1, cnt), 512, 0, stream>>>(
            adj, pt, sS, sT, bias, out, bb0);
    }
}

// Round 12
// 157.815 us; speedup vs baseline: 1.0958x; 1.0337x over previous
//
#include <hip/hip_runtime.h>
#include <hip/hip_bf16.h>
#include <math.h>

// Problem constants (BN, N, FIN, FO, H) from the reference
#define BN_   4
#define NN_   2048
#define FIN_  128
#define FO_   64
#define H_    4
#define D_    256   // FO*H

typedef __attribute__((ext_vector_type(8))) short bf16x8;   // 8 bf16 = 4 VGPRs
typedef __attribute__((ext_vector_type(4))) float floatx4;  // MFMA C/D frag

#define LOG2E 1.4426950408889634f

#if __has_builtin(__builtin_amdgcn_exp2f)
#define EXP2(x) __builtin_amdgcn_exp2f(x)
#else
#define EXP2(x) exp2f(x)
#endif

__device__ __forceinline__ float bf2f(short u) {
    union { unsigned int i; float f; } v;
    v.i = ((unsigned int)(unsigned short)u) << 16;
    return v.f;
}
__device__ __forceinline__ short f2bf(float f) {
    union { float f; unsigned int u; } v; v.f = f;
    unsigned int r = v.u + 0x7fffu + ((v.u >> 16) & 1u);  // RNE
    return (short)(unsigned short)(r >> 16);
}

// pack two floats to two bf16 (RNE) in one dword; elem0 in low 16 bits
#if defined(__BF16_MANT_DIG__)
typedef __bf16 bfr2 __attribute__((ext_vector_type(2)));
__device__ __forceinline__ unsigned int pack_bf16(float a, float b) {
    union { bfr2 h; unsigned int u; } v;
    v.h = (bfr2){(__bf16)a, (__bf16)b};
    return v.u;
}
#else
__device__ __forceinline__ unsigned int pack_bf16(float a, float b) {
    return ((unsigned int)(unsigned short)f2bf(a)) |
           (((unsigned int)(unsigned short)f2bf(b)) << 16);
}
#endif

// load 8 consecutive fp32 and round to a bf16x8 MFMA fragment
__device__ __forceinline__ bf16x8 load8f(const float* __restrict__ p) {
    floatx4 a = *(const floatx4*)p;
    floatx4 b = *(const floatx4*)(p + 4);
    union { bf16x8 v; unsigned int u[4]; } r;
    r.u[0] = pack_bf16(a[0], a[1]);
    r.u[1] = pack_bf16(a[2], a[3]);
    r.u[2] = pack_bf16(b[0], b[1]);
    r.u[3] = pack_bf16(b[2], b[3]);
    return r.v;
}

// attention score -> exp weight (bit-identical across rounds)
__device__ __forceinline__ float score_exp(float ssv, float stv, float av) {
    float s = ssv + stv;
    s = fmaxf(s, 0.2f * s);            // leaky_relu(0.2)
    return EXP2((s + av) * LOG2E);
}

// ---------------------------------------------------------------------------
// Kernel 1: projection -> PT2 (fragment-tiled bf16) + s_src/s_tgt.
// EXACT round-8 kernel (verified fast).
// PT2 layout:
//   elem(h, f, j) -> (h*64 + (j>>5))*2048 + (f>>4)*512 + ((j>>3)&3)*128
//                    + (f&15)*8 + (j&7)        [per-batch slab]
// ---------------------------------------------------------------------------
__global__ __launch_bounds__(256) void proj_kernel(
    const float* __restrict__ x,      // (BN, NN, FIN) fp32
    const float* __restrict__ wproj,  // (D, FIN) fp32
    const float* __restrict__ ssrc,   // (H, FO) fp32
    const float* __restrict__ stgt,   // (H, FO) fp32
    short* __restrict__ pt,           // (nb) PT2 slabs, 1 MiB each
    float* __restrict__ sS,           // (nb*H, NN) fp32
    float* __restrict__ sT,           // (nb*H, NN) fp32
    int b0)
{
    __shared__ short ptl[64][264];    // [f][j_local], +8 pad (33792 B)

    const int tid  = threadIdx.x;
    const int wave = tid >> 6;
    const int lane = tid & 63;
    const int l16  = lane & 15;
    const int quad = lane >> 4;

    const int b_rel = blockIdx.z;
    const int b  = b0 + b_rel;
    const int h  = blockIdx.y;            // head
    const int j0 = blockIdx.x * 256 + wave * 64;

    floatx4 acc[4][4];
#pragma unroll
    for (int mi = 0; mi < 4; ++mi)
#pragma unroll
        for (int nj = 0; nj < 4; ++nj)
            acc[mi][nj] = (floatx4){0.f, 0.f, 0.f, 0.f};

#pragma unroll
    for (int kc = 0; kc < 4; ++kc) {
        const int c = kc * 32 + quad * 8;
        bf16x8 afr[4], bfr[4];
#pragma unroll
        for (int mi = 0; mi < 4; ++mi) {
            int f = mi * 16 + l16;                // f within head
            int srow = f * H_ + h;                // W_proj row (flat d = f*H+h)
            afr[mi] = load8f(wproj + srow * FIN_ + c);
        }
#pragma unroll
        for (int nj = 0; nj < 4; ++nj) {
            int j = j0 + nj * 16 + l16;
            bfr[nj] = load8f(x + ((size_t)b * NN_ + j) * FIN_ + c);
        }
#pragma unroll
        for (int mi = 0; mi < 4; ++mi)
#pragma unroll
            for (int nj = 0; nj < 4; ++nj)
                acc[mi][nj] = __builtin_amdgcn_mfma_f32_16x16x32_bf16(
                    afr[mi], bfr[nj], acc[mi][nj], 0, 0, 0);
    }

    // ---- stage C-fragments into the [f][j_local] LDS tile ----
    // lane holds (f = mi*16 + quad*4 + r, j_local = wave*64 + nj*16 + l16)
#pragma unroll
    for (int mi = 0; mi < 4; ++mi)
#pragma unroll
        for (int r = 0; r < 4; ++r)
#pragma unroll
            for (int nj = 0; nj < 4; ++nj)
                ptl[mi * 16 + quad * 4 + r][wave * 64 + nj * 16 + l16] =
                    f2bf(acc[mi][nj][r]);

    // ---- score dot-products from fp32 accumulators (register-local) ----
    float wsv[4][4], wtv[4][4];
#pragma unroll
    for (int mi = 0; mi < 4; ++mi)
#pragma unroll
        for (int r = 0; r < 4; ++r) {
            int f = mi * 16 + quad * 4 + r;
            wsv[mi][r] = ssrc[h * FO_ + f];
            wtv[mi][r] = stgt[h * FO_ + f];
        }
    const size_t sbase = ((size_t)b_rel * H_ + h) * NN_;
#pragma unroll
    for (int nj = 0; nj < 4; ++nj) {
        float ps = 0.f, pg = 0.f;
#pragma unroll
        for (int mi = 0; mi < 4; ++mi)
#pragma unroll
            for (int r = 0; r < 4; ++r) {
                ps = fmaf(wsv[mi][r], acc[mi][nj][r], ps);
                pg = fmaf(wtv[mi][r], acc[mi][nj][r], pg);
            }
        ps += __shfl_xor(ps, 16, 64); ps += __shfl_xor(ps, 32, 64);
        pg += __shfl_xor(pg, 16, 64); pg += __shfl_xor(pg, 32, 64);
        if (quad == 0) {
            int j = j0 + nj * 16 + l16;
            sS[sbase + j] = ps;
            sT[sbase + j] = pg;
        }
    }

    __syncthreads();

    // ---- dense PT2 store: block's 32 KB range is CONTIGUOUS in PT2 ----
    const size_t base = ((size_t)b_rel * H_ + h) * (size_t)(64 * 2048)
                      + (size_t)(blockIdx.x * 8) * 2048;
#pragma unroll
    for (int p = 0; p < 8; ++p) {
        const int uid  = p * 256 + tid;           // 0..2047
        const int mi   = (uid >> 6) & 3;          // == wave
        const int l    = uid & 63;                // == lane
        const int tile = uid >> 8;                // wave-uniform
        const int f    = mi * 16 + (l & 15);
        const int js   = tile * 32 + (l >> 4) * 8;
        bf16x8 v = *(const bf16x8*)&ptl[f][js];   // 16B-aligned (264|8, js|8)
        *(bf16x8*)&pt[base + (size_t)uid * 8] = v;  // dense: lane*16B
    }
}

// ---------------------------------------------------------------------------
// Kernel 2: fused attention, 4 heads per block, i-tile = 32 (was 16).
//
// Round-12: reduce per-CU vmem instruction count (the five-point law: attn
// time ~ 56 cyc x vmem-instrs/CU; r11 showed locality is irrelevant).
// Doubling the i-tile shares each PT2 fragment load between TWO 16-row
// score fragments: vmem/CU 2304 -> ~1344 (20/jt x 8 jt x 8 waves, 1
// block/CU). acc[2][4][4] = 128 AGPRs (unified file, ~220 total < 256 cap
// at (512,2)). adj LDS tile doubles to [8][32][36]; LDS 69.6 KB (<160 KB,
// 1 block/CU by grid anyway). Per-output arithmetic sequence identical to
// round 8 -> bit-identical result. T1 XCD remap kept (FETCH -9 MB, r11).
// ---------------------------------------------------------------------------
#define RSTRIDE 65   // LDS row stride (pad +1 col to break bank alignment)
#define WSLOT   (RSTRIDE * 16 + 16)   // 1056 floats per wave slot

__global__ __launch_bounds__(512, 2) void attn_kernel(
    const float* __restrict__ adj,    // (BN, NN, NN) fp32
    const short* __restrict__ pt,     // PT2 slabs (see proj_kernel)
    const float* __restrict__ sS,     // (nb*H, NN) fp32
    const float* __restrict__ sT,     // (nb*H, NN) fp32
    const float* __restrict__ bias,   // (D,) fp32
    float* __restrict__ out,          // (BN, NN, D) fp32
    int b0)
{
    __shared__ union {
        struct {
            float adjs[8][32][36];    // per-wave adj tile (36864 B)
            float st[8][4][256];      // per-wave s_tgt slices (32768 B)
        } m;
        float red[8][WSLOT];          // cross-wave reduction (33792 B)
    } sm;

    const int tid  = threadIdx.x;
    const int w    = tid >> 6;        // wave = 256-wide j-slice
    const int lane = tid & 63;
    const int l16  = lane & 15;
    const int quad = lane >> 4;
    const int r8   = lane >> 3;       // 0..7  (adj stage row-in-group)
    const int c4   = (lane & 7) * 4;  // 0,4..28 (adj stage col, floats)

    // ---- T1 XCD-aware remap (identity unless full 4-batch grid) ----
    int bx = blockIdx.x, bz = blockIdx.z;
    if (gridDim.z == 4 && gridDim.x == 64) {
        const int flat = bx + 64 * bz;        // HW flat workgroup id (0..255)
        const int xcd  = flat & 7;            // round-robin XCD model
        bz = xcd >> 1;                        // batch: 2 XCDs per batch
        bx = (xcd & 1) * 32 + (flat >> 3);    // i-block within batch
    }
    const int b_rel = bz;
    const int b  = b0 + b_rel;
    const int i0 = bx * 32;

    const short* pt2_b = pt + (size_t)b_rel * H_ * (size_t)(64 * 2048);
    const size_t sb = (size_t)b_rel * H_ * NN_;

    // stage s_tgt slices for all 4 heads (wave-private; no barrier needed)
    {
        const int t = lane * 4;
#pragma unroll
        for (int h = 0; h < 4; ++h)
            *(floatx4*)&sm.m.st[w][h][t] =
                *(const floatx4*)&sT[sb + (size_t)h * NN_ + w * 256 + t];
    }

    // per-lane s_src for my two i-rows (sub*16 + l16), all heads
    float ssv[2][4];
#pragma unroll
    for (int sub = 0; sub < 2; ++sub)
#pragma unroll
        for (int h = 0; h < 4; ++h)
            ssv[sub][h] = sS[sb + (size_t)h * NN_ + i0 + sub * 16 + l16];

    // adj stage base: rows i0.., cols w*256..
    const float* adj_base = adj + ((size_t)b * NN_ + i0) * NN_ + w * 256;

    floatx4 acc[2][4][4];             // [i-sub][head][f-block], 128 regs
#pragma unroll
    for (int sub = 0; sub < 2; ++sub)
#pragma unroll
        for (int h = 0; h < 4; ++h)
#pragma unroll
            for (int K = 0; K < 4; ++K)
                acc[sub][h][K] = (floatx4){0.f, 0.f, 0.f, 0.f};
    float ls[2][4] = {{0.f, 0.f, 0.f, 0.f}, {0.f, 0.f, 0.f, 0.f}};

    // prologue: dense-load + stage adj tile jt=0 (32 rows)
    floatx4 ar0 = *(const floatx4*)(adj_base + (size_t)r8 * NN_ + c4);
    floatx4 ar1 = *(const floatx4*)(adj_base + (size_t)(8 + r8) * NN_ + c4);
    floatx4 ar2 = *(const floatx4*)(adj_base + (size_t)(16 + r8) * NN_ + c4);
    floatx4 ar3 = *(const floatx4*)(adj_base + (size_t)(24 + r8) * NN_ + c4);
    *(floatx4*)&sm.m.adjs[w][r8][c4]      = ar0;
    *(floatx4*)&sm.m.adjs[w][8 + r8][c4]  = ar1;
    *(floatx4*)&sm.m.adjs[w][16 + r8][c4] = ar2;
    *(floatx4*)&sm.m.adjs[w][24 + r8][c4] = ar3;

    const int lo8 = lane * 8;         // PT2 per-lane element offset

#pragma unroll
    for (int jt = 0; jt < 8; ++jt) {              // 8 iters x 32 j per wave
        const int o  = jt * 32;                   // static element offset
        const int qo = quad * 8;

        // T14 issue-early: dense global loads for the NEXT adj tile
        if (jt < 7) {
            ar0 = *(const floatx4*)(adj_base + (size_t)r8 * NN_ + o + 32 + c4);
            ar1 = *(const floatx4*)(adj_base + (size_t)(8 + r8) * NN_ + o + 32 + c4);
            ar2 = *(const floatx4*)(adj_base + (size_t)(16 + r8) * NN_ + o + 32 + c4);
            ar3 = *(const floatx4*)(adj_base + (size_t)(24 + r8) * NN_ + o + 32 + c4);
        }

        // A-values for both i-subtiles from LDS (wave-private, staged)
        floatx4 ajA[2], ajB[2];
#pragma unroll
        for (int sub = 0; sub < 2; ++sub) {
            ajA[sub] = *(const floatx4*)&sm.m.adjs[w][sub * 16 + l16][qo];
            ajB[sub] = *(const floatx4*)&sm.m.adjs[w][sub * 16 + l16][qo + 4];
        }

#pragma unroll
        for (int u = 0; u < 4; ++u) {
            // dense 1 KB fragment loads from PT2 (uniform base + lane*16B),
            // shared by BOTH i-subtiles (the round-12 reuse lever)
            const short* fb = pt2_b + ((size_t)u * 64 + (w * 8 + jt)) * 2048 + lo8;
            bf16x8 bfr[4];
#pragma unroll
            for (int K = 0; K < 4; ++K)
                bfr[K] = *(const bf16x8*)(fb + K * 512);

            const float* stp = &sm.m.st[w][u][qo];
            floatx4 stA = *(const floatx4*)(stp + o);
            floatx4 stB = *(const floatx4*)(stp + o + 4);

#pragma unroll
            for (int sub = 0; sub < 2; ++sub) {
                const float sv = ssv[sub][u];
                float w0 = score_exp(sv, stA[0], ajA[sub][0]);
                float w1 = score_exp(sv, stA[1], ajA[sub][1]);
                float w2 = score_exp(sv, stA[2], ajA[sub][2]);
                float w3 = score_exp(sv, stA[3], ajA[sub][3]);
                float w4 = score_exp(sv, stB[0], ajB[sub][0]);
                float w5 = score_exp(sv, stB[1], ajB[sub][1]);
                float w6 = score_exp(sv, stB[2], ajB[sub][2]);
                float w7 = score_exp(sv, stB[3], ajB[sub][3]);
                ls[sub][u] += ((w0 + w1) + (w2 + w3)) + ((w4 + w5) + (w6 + w7));
                union { bf16x8 v; unsigned int u4[4]; } a0;
                a0.u4[0] = pack_bf16(w0, w1);
                a0.u4[1] = pack_bf16(w2, w3);
                a0.u4[2] = pack_bf16(w4, w5);
                a0.u4[3] = pack_bf16(w6, w7);
#pragma unroll
                for (int K = 0; K < 4; ++K)
                    acc[sub][u][K] = __builtin_amdgcn_mfma_f32_16x16x32_bf16(
                        a0.v, bfr[K], acc[sub][u][K], 0, 0, 0);
            }
        }

        // T14 write-late: stage next tile after this tile's LDS reads
        if (jt < 7) {
            *(floatx4*)&sm.m.adjs[w][r8][c4]      = ar0;
            *(floatx4*)&sm.m.adjs[w][8 + r8][c4]  = ar1;
            *(floatx4*)&sm.m.adjs[w][16 + r8][c4] = ar2;
            *(floatx4*)&sm.m.adjs[w][24 + r8][c4] = ar3;
        }
    }

    // wave-local row-sums over quads (row = sub*16 + l16 in A-layout)
#pragma unroll
    for (int sub = 0; sub < 2; ++sub)
#pragma unroll
        for (int h = 0; h < 4; ++h) {
            ls[sub][h] += __shfl_xor(ls[sub][h], 16, 64);
            ls[sub][h] += __shfl_xor(ls[sub][h], 32, 64);
        }

    // epilogue: 8 chunks (sub x head) of 16 rows; 8-wave LDS reduction each
#pragma unroll
    for (int sub = 0; sub < 2; ++sub)
#pragma unroll
    for (int h = 0; h < 4; ++h) {
        __syncthreads();   // first: all main-loop LDS reads done; then: prev chunk
#pragma unroll
        for (int K = 0; K < 4; ++K)
#pragma unroll
            for (int r = 0; r < 4; ++r)
                sm.red[w][(quad * 4 + r) * RSTRIDE + K * 16 + l16] = acc[sub][h][K][r];
        if (quad == 0)
            sm.red[w][16 * RSTRIDE + l16] = ls[sub][h];
        __syncthreads();
#pragma unroll
        for (int p = 0; p < 2; ++p) {
            int e   = tid + p * 512;
            int row = e >> 6;
            int col = e & 63;
            float s = 0.f, l = 0.f;
#pragma unroll
            for (int ww = 0; ww < 8; ++ww) {
                s += sm.red[ww][row * RSTRIDE + col];
                l += sm.red[ww][16 * RSTRIDE + row];
            }
            float v = s / l + bias[h * FO_ + col];
            v = (v > 0.f) ? v : expm1f(v);        // elu (fp32 out)
            out[((size_t)b * NN_ + i0 + sub * 16 + row) * D_ + h * FO_ + col] = v;
        }
    }
}

// ---------------------------------------------------------------------------
extern "C" void kernel_launch(void* const* d_in, const int* in_sizes, int n_in,
                              void* d_out, int out_size, void* d_ws, size_t ws_size,
                              hipStream_t stream) {
    const float* x     = (const float*)d_in[0];   // (4,2048,128) fp32
    const float* adj   = (const float*)d_in[1];   // (4,2048,2048) fp32
    const float* wproj = (const float*)d_in[2];   // (256,128) fp32
    const float* ssrc  = (const float*)d_in[3];   // (4,64) fp32
    const float* stgt  = (const float*)d_in[4];   // (4,64) fp32
    const float* bias  = (const float*)d_in[5];   // (256,) fp32
    float* out = (float*)d_out;                   // (4,2048,256) fp32

    // ws layout per batch: PT2 slab (1 MiB) + s_src/s_tgt (64 KiB)
    const size_t SLAB  = (size_t)D_ * NN_ * 2;          // bf16 PT2
    const size_t SSLAB = (size_t)2 * H_ * NN_ * 4;      // fp32 sS+sT
    int nb = (int)(ws_size / (SLAB + SSLAB));
    if (nb < 1) nb = 1;
    if (nb > 4) nb = 4;

    short* pt = (short*)d_ws;
    float* sv = (float*)((char*)d_ws + (size_t)nb * SLAB);
    float* sS = sv;
    float* sT = sv + (size_t)nb * H_ * NN_;

    for (int bb0 = 0; bb0 < BN_; bb0 += nb) {
        int cnt = (BN_ - bb0 < nb) ? (BN_ - bb0) : nb;
        proj_kernel<<<dim3(NN_ / 256, H_, cnt), 256, 0, stream>>>(
            x, wproj, ssrc, stgt, pt, sS, sT, bb0);
        attn_kernel<<<dim3(NN_ / 32, 1, cnt), 512, 0, stream>>>(
            adj, pt, sS, sT, bias, out, bb0);
    }
}